// Round 7
// baseline (277.990 us; speedup 1.0000x reference)
//
#include <hip/hip_runtime.h>
#include <cfloat>

// Problem constants
#define B_   16
#define C_   256
#define HW_  4096      // 64*64
#define N_   65536     // B_*HW_
#define K_   1024

// Output layout (float32, concatenated flat in return order):
//  [0] loss | [1,+16777216) quantized (b c h w) | [16777217] perplexity
//  [16777218,+67108864) encodings (N,K)
#define OUT_QOFF   1
#define OUT_POFF   16777217
#define OUT_EOFF   16777218

#define MARGIN 1.5f

typedef __bf16 bf16x8 __attribute__((ext_vector_type(8)));
typedef float  f32x4  __attribute__((ext_vector_type(4)));

// ---------------------------------------------------------------- bf16 split
__device__ inline ushort f2bf(float f) {
    union { float f; unsigned u; } a; a.f = f;
    unsigned u = a.u;
    unsigned r = (u + 0x7fffu + ((u >> 16) & 1u)) >> 16;   // RNE
    return (ushort)r;
}
__device__ inline float bf2f(ushort u) {
    union { float f; unsigned u; } a; a.u = ((unsigned)u) << 16; return a.f;
}

// ------------------------------------- prep: pack eh (1 split) + enorm + cnt0
// Packed layout per step s in [0,64): s = (k>>5)*2 + (c>>7); within 8192-B
// block: [cg(16)][code(32)][ci(8)] bf16.
__global__ __launch_bounds__(256) void k_prep(const float* __restrict__ emb,
                                              char* __restrict__ epk,
                                              float* __restrict__ enorm,
                                              int* __restrict__ counts) {
    const int k = blockIdx.x;
    const int c = threadIdx.x;
    float v = emb[k * C_ + c];
    ushort h = f2bf(v);
    int s  = (k >> 5) * 2 + (c >> 7);
    int cl = c & 127;
    size_t off = (size_t)s * 8192 + (size_t)((cl >> 3) * 512 + (k & 31) * 16 + (cl & 7) * 2);
    *(ushort*)(epk + off) = h;
    float sq = v * v;
    __shared__ float red[4];
#pragma unroll
    for (int o = 32; o > 0; o >>= 1) sq += __shfl_down(sq, o);
    if ((c & 63) == 0) red[c >> 6] = sq;
    __syncthreads();
    if (c == 0) {
        enorm[k]  = (red[0] + red[1]) + (red[2] + red[3]);
        counts[k] = 0;
    }
}

// ------------------------------------------------- pass 1: approx + candidates
// Block: 128 rows x 1024 codes, 4 waves (32 rows each = 2 row-frags of 16).
// A (2 bf16 splits, exact to 2^-18) in regs; B = eh only, double-buffered in
// LDS. acc = (ah+am)*eh ~= x*eh. Per lane keep best + 2-min stash; emit all
// entries within MARGIN of the row min as candidates for exact refine.
__global__ __launch_bounds__(256, 2) void k_argmin_mfma(const float* __restrict__ x,
                                                        const char* __restrict__ epk,
                                                        const float* __restrict__ enorm,
                                                        ushort* __restrict__ cand) {
    __shared__ __align__(16) char Bs[2][8192];
    __shared__ float En[K_];

    const int tid  = threadIdx.x;
    const int lane = tid & 63;
    const int wid  = tid >> 6;
    const int l15  = lane & 15;
    const int kg   = lane >> 4;
    const int row0 = blockIdx.x * 128;
    const int cpOff = wid * 1024 + lane * 16;   // wave's copy offset (2KB/wave/step)

    for (int i = tid; i < K_; i += 256) En[i] = enorm[i];

    // ---- build A fragments (rows = wid*32 + f*16 + l15, k-elems = kg*8+i)
    union FU { bf16x8 v; ushort u[8]; };
    FU Ah[2][8], Am[2][8];
#pragma unroll
    for (int f = 0; f < 2; ++f) {
        const int n  = row0 + wid * 32 + f * 16 + l15;
        const int b  = n >> 12, hw = n & 4095;
        const float* xb = x + (size_t)b * (C_ * HW_) + hw;
#pragma unroll
        for (int cb = 0; cb < 8; ++cb) {
#pragma unroll
            for (int i = 0; i < 8; ++i) {
                float v = xb[(cb * 32 + kg * 8 + i) * HW_];
                ushort h = f2bf(v);
                ushort m = f2bf(v - bf2f(h));
                Ah[f][cb].u[i] = h; Am[f][cb].u[i] = m;
            }
        }
    }
    __syncthreads();

    // ---- stage step 0 (2 x 16B per thread; src/dst share offset)
    {
        const char* src = epk + (size_t)cpOff;
        char* dstb = &Bs[0][0] + cpOff;
#pragma unroll
        for (int j = 0; j < 2; ++j) {
            __builtin_amdgcn_global_load_lds(
                (const __attribute__((address_space(1))) void*)(src + j * 4096),
                (__attribute__((address_space(3))) void*)(dstb + j * 4096), 16, 0, 0);
        }
    }

    // per-lane argmin state: 8 row-slots (f*4+r)
    float bd[8], s0d[8], s1d[8];
    int   bi[8], s0i[8], s1i[8];
#pragma unroll
    for (int t = 0; t < 8; ++t) {
        bd[t] = FLT_MAX; s0d[t] = FLT_MAX; s1d[t] = FLT_MAX;
        bi[t] = 0xFFFF;  s0i[t] = 0xFFFF;  s1i[t] = 0xFFFF;
    }
    const int laneB = kg * 512 + l15 * 16;
    const f32x4 zero = {0.f, 0.f, 0.f, 0.f};
    f32x4 accA0, accB0, accA1, accB1;

#define STEP(H, IS_LAST) do {                                                       \
    if (!(IS_LAST)) {                                                               \
        int sn = 2 * kt + (H) + 1;                                                  \
        const char* src = epk + (size_t)sn * 8192 + (size_t)cpOff;                  \
        char* dstb = &Bs[1 - (H)][0] + cpOff;                                       \
        _Pragma("unroll")                                                           \
        for (int j = 0; j < 2; ++j) {                                               \
            __builtin_amdgcn_global_load_lds(                                       \
                (const __attribute__((address_space(1))) void*)(src + j * 4096),    \
                (__attribute__((address_space(3))) void*)(dstb + j * 4096),         \
                16, 0, 0);                                                          \
        }                                                                           \
        asm volatile("s_waitcnt vmcnt(2)" ::: "memory");                            \
    } else {                                                                        \
        asm volatile("s_waitcnt vmcnt(0)" ::: "memory");                            \
    }                                                                               \
    __builtin_amdgcn_s_barrier();                                                   \
    asm volatile("" ::: "memory");                                                  \
    {                                                                               \
        const char* bbase = &Bs[(H)][0] + laneB;                                    \
        _Pragma("unroll")                                                           \
        for (int cbl = 0; cbl < 4; ++cbl) {                                         \
            const char* bp = bbase + cbl * 2048;                                    \
            bf16x8 Bh0 = *(const bf16x8*)(bp);                                      \
            bf16x8 Bh1 = *(const bf16x8*)(bp + 256);                                \
            const bf16x8 a0h = Ah[0][(H) * 4 + cbl].v;                              \
            const bf16x8 a0m = Am[0][(H) * 4 + cbl].v;                              \
            const bf16x8 a1h = Ah[1][(H) * 4 + cbl].v;                              \
            const bf16x8 a1m = Am[1][(H) * 4 + cbl].v;                              \
            accA0 = __builtin_amdgcn_mfma_f32_16x16x32_bf16(a0h, Bh0, accA0, 0,0,0);\
            accB0 = __builtin_amdgcn_mfma_f32_16x16x32_bf16(a0h, Bh1, accB0, 0,0,0);\
            accA1 = __builtin_amdgcn_mfma_f32_16x16x32_bf16(a1h, Bh0, accA1, 0,0,0);\
            accB1 = __builtin_amdgcn_mfma_f32_16x16x32_bf16(a1h, Bh1, accB1, 0,0,0);\
            accA0 = __builtin_amdgcn_mfma_f32_16x16x32_bf16(a0m, Bh0, accA0, 0,0,0);\
            accB0 = __builtin_amdgcn_mfma_f32_16x16x32_bf16(a0m, Bh1, accB0, 0,0,0);\
            accA1 = __builtin_amdgcn_mfma_f32_16x16x32_bf16(a1m, Bh0, accA1, 0,0,0);\
            accB1 = __builtin_amdgcn_mfma_f32_16x16x32_bf16(a1m, Bh1, accB1, 0,0,0);\
        }                                                                           \
    }                                                                               \
    asm volatile("s_waitcnt lgkmcnt(0)" ::: "memory");                              \
    __builtin_amdgcn_s_barrier();                                                   \
} while (0)

// best/stash update: on new best push old best; else push d. Stash keeps the
// two smallest pushed values -> per lane we retain the 3 smallest distances.
#define UPD(d_, c_, t_) do {                                                        \
    float d = (d_); int c = (c_);                                                   \
    bool nb = d < bd[t_];                                                           \
    float pd = nb ? bd[t_] : d;  int pi = nb ? bi[t_] : c;                          \
    if (nb) { bd[t_] = d; bi[t_] = c; }                                             \
    bool l0 = pd < s0d[t_];                                                         \
    float td = l0 ? s0d[t_] : pd;  int ti = l0 ? s0i[t_] : pi;                      \
    if (l0) { s0d[t_] = pd; s0i[t_] = pi; }                                         \
    if (td < s1d[t_]) { s1d[t_] = td; s1i[t_] = ti; }                               \
} while (0)

    for (int kt = 0; kt < 32; ++kt) {
        accA0 = zero; accB0 = zero; accA1 = zero; accB1 = zero;
        STEP(0, false);
        STEP(1, kt == 31);
        const int cA = kt * 32 + l15;
        const int cB = cA + 16;
        const float enA = En[cA], enB = En[cB];
#pragma unroll
        for (int r = 0; r < 4; ++r) {
            UPD(enA - 2.0f * accA0[r], cA, r);
            UPD(enB - 2.0f * accB0[r], cB, r);
            UPD(enA - 2.0f * accA1[r], cA, 4 + r);
            UPD(enB - 2.0f * accB1[r], cB, 4 + r);
        }
    }
#undef STEP
#undef UPD

    // emit candidates: row min across 16 lanes, filter by margin
#pragma unroll
    for (int f = 0; f < 2; ++f) {
#pragma unroll
        for (int r = 0; r < 4; ++r) {
            const int t = f * 4 + r;
            float gb = bd[t];
#pragma unroll
            for (int m = 1; m < 16; m <<= 1) {
                float o = __shfl_xor(gb, m);
                gb = (o < gb) ? o : gb;
            }
            const float thr = gb + MARGIN;
            ushort e0 = (bd[t]  <= thr) ? (ushort)bi[t]  : (ushort)0xFFFF;
            ushort e1 = (s0d[t] <= thr) ? (ushort)s0i[t] : (ushort)0xFFFF;
            ushort e2 = (s1d[t] <= thr) ? (ushort)s1i[t] : (ushort)0xFFFF;
            const int n = row0 + wid * 32 + f * 16 + kg * 4 + r;
            ushort* cp = cand + ((size_t)n * 64 + l15 * 4);
            cp[0] = e0; cp[1] = e1; cp[2] = e2; cp[3] = 0xFFFF;
        }
    }
}

// ---------------- pass 2: exact refine + quantized + loss + counts (fused)
// Block: 32 rows (one b, 32 consecutive hw). x^T staged in LDS; exact fp32
// distances for the few candidates per row; first-occurrence tie-break.
__global__ __launch_bounds__(256, 2) void k_refine(const float* __restrict__ x,
                                                   const float* __restrict__ emb,
                                                   const float* __restrict__ enorm,
                                                   const ushort* __restrict__ cand,
                                                   int* __restrict__ bestIdx,
                                                   int* __restrict__ counts,
                                                   float* __restrict__ outq,
                                                   float* __restrict__ partials) {
    __shared__ float A2[32][257];
    __shared__ float E[32][257];
    __shared__ int bi_s[32];

    const int tid  = threadIdx.x;
    const int lane = tid & 63;
    const int wid  = tid >> 6;
    const int bb   = blockIdx.x >> 7;
    const int hw0  = (blockIdx.x & 127) * 32;
    const size_t xbase = (size_t)bb * (C_ * HW_);

    // stage x^T tile (coalesced float4 over hw)
#pragma unroll
    for (int it = 0; it < 8; ++it) {
        int idx = it * 256 + tid;
        int c = idx >> 3, q = idx & 7;
        float4 v = *(const float4*)&x[xbase + (size_t)c * HW_ + hw0 + q * 4];
        A2[q * 4 + 0][c] = v.x; A2[q * 4 + 1][c] = v.y;
        A2[q * 4 + 2][c] = v.z; A2[q * 4 + 3][c] = v.w;
    }
    __syncthreads();

    // refine: wave wid handles rows wid*8 .. wid*8+7
    for (int rr = 0; rr < 8; ++rr) {
        const int r = wid * 8 + rr;
        const int n = bb * HW_ + hw0 + r;
        uint2 myu = ((const uint2*)cand)[(size_t)n * 16 + (lane & 15)];
        float bd = FLT_MAX; int bidx = 0x7FFFFFFF;
        for (int sl = 0; sl < 16; ++sl) {
            unsigned ux = __shfl(myu.x, sl);
            unsigned uy = __shfl(myu.y, sl);
#pragma unroll
            for (int j = 0; j < 3; ++j) {
                unsigned idxv = (j == 0) ? (ux & 0xFFFFu) : (j == 1) ? (ux >> 16) : (uy & 0xFFFFu);
                if (idxv == 0xFFFFu) continue;
                float4 ev = *(const float4*)&emb[(size_t)idxv * C_ + lane * 4];
                float s = ev.x * A2[r][lane * 4 + 0] + ev.y * A2[r][lane * 4 + 1]
                        + ev.z * A2[r][lane * 4 + 2] + ev.w * A2[r][lane * 4 + 3];
#pragma unroll
                for (int m = 1; m < 64; m <<= 1) s += __shfl_xor(s, m);
                float d = enorm[idxv] - 2.0f * s;
                if (d < bd || (d == bd && (int)idxv < bidx)) { bd = d; bidx = (int)idxv; }
            }
        }
        if (lane == 0) {
            bi_s[r] = bidx;
            bestIdx[n] = bidx;
            atomicAdd(&counts[bidx], 1);
        }
    }
    __syncthreads();

    // stage selected code rows (coalesced from L2-hot emb)
#pragma unroll
    for (int it = 0; it < 8; ++it) {
        int idx = it * 256 + tid;
        int r = idx >> 6, cq = idx & 63;
        float4 ev = *(const float4*)&emb[(size_t)bi_s[r] * C_ + cq * 4];
        E[r][cq * 4 + 0] = ev.x; E[r][cq * 4 + 1] = ev.y;
        E[r][cq * 4 + 2] = ev.z; E[r][cq * 4 + 3] = ev.w;
    }
    __syncthreads();

    // quantized (x + (q - x)) + loss partials
    const int r  = tid & 31;
    const int ch = tid >> 5;   // 0..7
    float lsum = 0.f;
    float* oq = outq + xbase + hw0 + r;
#pragma unroll 8
    for (int it = 0; it < 32; ++it) {
        int c = it * 8 + ch;
        float xv = A2[r][c], qv = E[r][c];
        float o = xv + (qv - xv);
        float dd = qv - xv;
        lsum += dd * dd;
        __builtin_nontemporal_store(o, oq + (size_t)c * HW_);
    }
    __shared__ float red[4];
#pragma unroll
    for (int o = 32; o > 0; o >>= 1) lsum += __shfl_down(lsum, o);
    if ((tid & 63) == 0) red[tid >> 6] = lsum;
    __syncthreads();
    if (tid == 0) partials[blockIdx.x] = (red[0] + red[1]) + (red[2] + red[3]);
}

// ------------------------------------------------------- one-hot encodings
__global__ __launch_bounds__(256) void k_enc(const int* __restrict__ bestIdx,
                                             float* __restrict__ enc) {
    const int k4 = threadIdx.x * 4;
    int row = blockIdx.x * 8;
#pragma unroll
    for (int j = 0; j < 8; ++j, ++row) {
        int idv = bestIdx[row];
        f32x4 v;
        v.x = (k4 + 0 == idv) ? 1.0f : 0.0f;
        v.y = (k4 + 1 == idv) ? 1.0f : 0.0f;
        v.z = (k4 + 2 == idv) ? 1.0f : 0.0f;
        v.w = (k4 + 3 == idv) ? 1.0f : 0.0f;
        __builtin_nontemporal_store(v, (f32x4*)&enc[(size_t)row * K_ + k4]);
    }
}

// ----------------------------------------------------------------- finalize
__global__ __launch_bounds__(256) void k_final(const float* __restrict__ partials,
                                               const int* __restrict__ counts,
                                               float* __restrict__ out) {
    const int tid = threadIdx.x;
    float s = 0.f;
    for (int i = tid; i < 2048; i += 256) s += partials[i];
    float h = 0.f;
    for (int k = tid; k < K_; k += 256) {
        float p = (float)counts[k] * (1.0f / 65536.0f);
        h += p * logf(p + 1e-10f);
    }
    __shared__ float redS[4], redH[4];
#pragma unroll
    for (int o = 32; o > 0; o >>= 1) {
        s += __shfl_down(s, o);
        h += __shfl_down(h, o);
    }
    if ((tid & 63) == 0) { redS[tid >> 6] = s; redH[tid >> 6] = h; }
    __syncthreads();
    if (tid == 0) {
        float S = (redS[0] + redS[1]) + (redS[2] + redS[3]);
        float H = (redH[0] + redH[1]) + (redH[2] + redH[3]);
        out[0]        = 0.25f * S / 16777216.0f;
        out[OUT_POFF] = expf(-H);
    }
}

extern "C" void kernel_launch(void* const* d_in, const int* in_sizes, int n_in,
                              void* d_out, int out_size, void* d_ws, size_t ws_size,
                              hipStream_t stream) {
    const float* x   = (const float*)d_in[0];
    const float* emb = (const float*)d_in[1];
    float* out = (float*)d_out;
    char*  ws  = (char*)d_ws;

    // Workspace layout
    int*   bestIdx  = (int*)(ws);                 // 262144 B
    int*   counts   = (int*)(ws + 262144);        //   4096 B
    float* partials = (float*)(ws + 266240);      //   8192 B
    float* enorm    = (float*)(ws + 274432);      //   4096 B
    char*  epk      = ws + 278528;                // 524288 B packed eh
    // candidate lists (8 MB) live in the encodings output region; k_enc
    // overwrites it afterwards.
    ushort* cand = (ushort*)(out + OUT_EOFF);

    k_prep       <<<K_,       256, 0, stream>>>(emb, epk, enorm, counts);
    k_argmin_mfma<<<N_ / 128, 256, 0, stream>>>(x, epk, enorm, cand);
    k_refine     <<<N_ / 32,  256, 0, stream>>>(x, emb, enorm, cand, bestIdx,
                                                counts, out + OUT_QOFF, partials);
    k_enc        <<<8192,     256, 0, stream>>>(bestIdx, out + OUT_EOFF);
    k_final      <<<1,        256, 0, stream>>>(partials, counts, out);
}